// Round 1
// baseline (398.940 us; speedup 1.0000x reference)
//
#include <hip/hip_runtime.h>
#include <math.h>

typedef __attribute__((ext_vector_type(8))) short bf16x8;
typedef __attribute__((ext_vector_type(4))) float f32x4;

static __device__ __forceinline__ short f2bf(float x){
  union { float f; unsigned u; } a; a.f = x;
  unsigned r = a.u + 0x7fffu + ((a.u >> 16) & 1u);
  return (short)(r >> 16);
}

// out[i][j] = (i < IC && j < IR) ? in[j][i] : 0 ; out dims [OR][OC] (bf16)
__global__ __launch_bounds__(256) void transpose_bf16_kernel(
    const float* __restrict__ in, short* __restrict__ out,
    int IR, int IC, int OR, int OC)
{
  __shared__ float tile[32][33];
  int i0 = blockIdx.x * 32;
  int j0 = blockIdx.y * 32;
  int tx = threadIdx.x, ty = threadIdx.y;
  #pragma unroll
  for (int r = 0; r < 32; r += 8){
    int j = j0 + ty + r, i = i0 + tx;
    tile[ty + r][tx] = (j < IR && i < IC) ? in[(size_t)j * IC + i] : 0.f;
  }
  __syncthreads();
  #pragma unroll
  for (int r = 0; r < 32; r += 8){
    int oi = i0 + ty + r, oj = j0 + tx;
    if (oi < OR && oj < OC) out[(size_t)oi * OC + oj] = f2bf(tile[tx][ty + r]);
  }
}

// one block per row of 1024; h = x / (sqrt(mean(x^2)) + eps) * g  -> bf16
__global__ __launch_bounds__(256) void rmsnorm_kernel(
    const float* __restrict__ x, const float* __restrict__ g, short* __restrict__ out)
{
  int row = blockIdx.x, tid = threadIdx.x;
  const float4* xr = (const float4*)(x + (size_t)row * 1024);
  float4 v = xr[tid];
  float ss = v.x*v.x + v.y*v.y + v.z*v.z + v.w*v.w;
  #pragma unroll
  for (int m = 1; m < 64; m <<= 1) ss += __shfl_xor(ss, m, 64);
  __shared__ float sm[4];
  if ((tid & 63) == 0) sm[tid >> 6] = ss;
  __syncthreads();
  float tot = sm[0] + sm[1] + sm[2] + sm[3];
  float inv = 1.f / (sqrtf(tot * (1.f/1024.f)) + 1e-5f);
  float4 gv = ((const float4*)g)[tid];
  short4 o;
  o.x = f2bf(v.x * inv * gv.x);
  o.y = f2bf(v.y * inv * gv.y);
  o.z = f2bf(v.z * inv * gv.z);
  o.w = f2bf(v.w * inv * gv.w);
  *(short4*)(out + (size_t)row * 1024 + tid * 4) = o;
}

enum { EPI_F32 = 0, EPI_RESID = 1, EPI_QKV = 2, EPI_GATED = 3 };

// C[M,N] = A[M,K](bf16,row-major) * Bt[N,K](bf16,row-major)^T ; 128x128 tile, 4 waves,
// global_load_lds width-16 staging (m97 structure). M%128==0, N%128==0, K%32==0.
template<int EPI>
__global__ __launch_bounds__(256) void gemm128_kernel(
    const short* __restrict__ A, const short* __restrict__ Bt,
    int M, int N, int K,
    float* __restrict__ outF, short* __restrict__ outB,
    const float* __restrict__ resid, const float* __restrict__ Gprev,
    short* __restrict__ qb, short* __restrict__ kb, short* __restrict__ vb)
{
  __shared__ short As[128 * 32];
  __shared__ short Bs[128 * 32];
  int tid = threadIdx.x, lane = tid & 63;
  int wave = tid >> 6, wr = wave >> 1, wc = wave & 1;
  int m0 = blockIdx.x * 128, n0 = blockIdx.y * 128;

  f32x4 acc[4][4];
  #pragma unroll
  for (int i = 0; i < 4; ++i)
    #pragma unroll
    for (int j = 0; j < 4; ++j) acc[i][j] = f32x4{0.f, 0.f, 0.f, 0.f};

  int off0 = tid * 16;          // byte offset in 8KB tile
  int off1 = off0 + 4096;
  int ar0 = off0 >> 6, ac0 = (off0 & 63) >> 1;
  int ar1 = off1 >> 6, ac1 = (off1 & 63) >> 1;
  const short* Ab = A + (size_t)m0 * K;
  const short* Bb = Bt + (size_t)n0 * K;
  int la = lane & 15, lb = (lane >> 4) * 8;

  for (int k0 = 0; k0 < K; k0 += 32){
    __syncthreads();
    __builtin_amdgcn_global_load_lds((const __attribute__((address_space(1))) void*)(Ab + (size_t)ar0 * K + k0 + ac0),
                                     (__attribute__((address_space(3))) void*)((char*)As + off0), 16, 0, 0);
    __builtin_amdgcn_global_load_lds((const __attribute__((address_space(1))) void*)(Ab + (size_t)ar1 * K + k0 + ac1),
                                     (__attribute__((address_space(3))) void*)((char*)As + off1), 16, 0, 0);
    __builtin_amdgcn_global_load_lds((const __attribute__((address_space(1))) void*)(Bb + (size_t)ar0 * K + k0 + ac0),
                                     (__attribute__((address_space(3))) void*)((char*)Bs + off0), 16, 0, 0);
    __builtin_amdgcn_global_load_lds((const __attribute__((address_space(1))) void*)(Bb + (size_t)ar1 * K + k0 + ac1),
                                     (__attribute__((address_space(3))) void*)((char*)Bs + off1), 16, 0, 0);
    __syncthreads();

    bf16x8 a[4], b[4];
    #pragma unroll
    for (int i = 0; i < 4; ++i)
      a[i] = *(const bf16x8*)(As + (wr * 64 + i * 16 + la) * 32 + lb);
    #pragma unroll
    for (int j = 0; j < 4; ++j)
      b[j] = *(const bf16x8*)(Bs + (wc * 64 + j * 16 + la) * 32 + lb);
    #pragma unroll
    for (int i = 0; i < 4; ++i)
      #pragma unroll
      for (int j = 0; j < 4; ++j)
        acc[i][j] = __builtin_amdgcn_mfma_f32_16x16x32_bf16(a[i], b[j], acc[i][j], 0, 0, 0);
  }

  int rbase = m0 + wr * 64 + (lane >> 4) * 4;
  int cbase = n0 + wc * 64 + la;
  #pragma unroll
  for (int i = 0; i < 4; ++i){
    #pragma unroll
    for (int j = 0; j < 4; ++j){
      #pragma unroll
      for (int r = 0; r < 4; ++r){
        int row = rbase + i * 16 + r;
        int col = cbase + j * 16;
        float v = acc[i][j][r];
        size_t idx = (size_t)row * N + col;
        if (EPI == EPI_F32){
          outF[idx] = v;
        } else if (EPI == EPI_RESID){
          outF[idx] = v + resid[idx];
        } else if (EPI == EPI_GATED){
          float gg = Gprev[idx];
          float s = gg / (1.f + __expf(-gg));
          outB[idx] = f2bf(s * v);
        } else { // EPI_QKV: scatter to q/k/v [B,H,T,64]; fold 1/sqrt(C)=1/32 into q (exact pow2)
          int which = col >> 10;
          int hh = (col & 1023) >> 6;
          int d = col & 63;
          int bb = row >> 11, tt = row & 2047;
          size_t o = (((size_t)(bb * 16 + hh) * 2048) + tt) * 64 + d;
          short* dst = (which == 0) ? qb : (which == 1) ? kb : vb;
          dst[o] = f2bf(which == 0 ? v * 0.03125f : v);
        }
      }
    }
  }
}

// flash attention: block=(qtile of 64, b*h); 4 waves x 16 q-rows; KV tiles of 64.
// q already scaled by 1/32. scores = q.k + slope*(kv-q), causal.
__global__ __launch_bounds__(256) void attn_kernel(
    const short* __restrict__ qb, const short* __restrict__ kb,
    const short* __restrict__ vb, short* __restrict__ concat)
{
  const int T = 2048;
  int bh = blockIdx.y;
  int h = bh & 15, b = bh >> 4;
  int q0 = blockIdx.x * 64;
  int tid = threadIdx.x, lane = tid & 63, wave = tid >> 6;
  int la = lane & 15, lg = lane >> 4;

  const short* Q  = qb + (size_t)bh * T * 64;
  const short* Kg = kb + (size_t)bh * T * 64;
  const short* Vg = vb + (size_t)bh * T * 64;

  __shared__ short Ks[64][80];      // [kv][d], padded (bank spread, 16B-aligned rows)
  __shared__ short Vt[64][80];      // [d][kv] transposed
  __shared__ short Ps[4][16][80];   // per-wave P tile

  int qr = q0 + wave * 16 + la;
  bf16x8 qf[2];
  qf[0] = *(const bf16x8*)(Q + (size_t)qr * 64 + lg * 8);
  qf[1] = *(const bf16x8*)(Q + (size_t)qr * 64 + 32 + lg * 8);

  f32x4 o[4];
  float m_run[4], l_run[4];
  #pragma unroll
  for (int i = 0; i < 4; ++i){ o[i] = f32x4{0.f,0.f,0.f,0.f}; m_run[i] = -1e30f; l_run[i] = 0.f; }

  float slope = exp2f(-0.5f * (float)(h + 1));
  int qpb = q0 + wave * 16 + lg * 4;
  int srow = tid >> 2;
  int scol = (tid & 3) * 16;

  int ntiles = blockIdx.x + 1;
  for (int t = 0; t < ntiles; ++t){
    int kv0 = t * 64;
    __syncthreads();
    { // stage K row-major, V transposed
      const short* kp = Kg + (size_t)(kv0 + srow) * 64 + scol;
      bf16x8 k0 = *(const bf16x8*)kp;
      bf16x8 k1 = *(const bf16x8*)(kp + 8);
      *(bf16x8*)&Ks[srow][scol] = k0;
      *(bf16x8*)&Ks[srow][scol + 8] = k1;
      const short* vp = Vg + (size_t)(kv0 + srow) * 64 + scol;
      bf16x8 v0 = *(const bf16x8*)vp;
      bf16x8 v1 = *(const bf16x8*)(vp + 8);
      #pragma unroll
      for (int j2 = 0; j2 < 8; ++j2) Vt[scol + j2][srow] = v0[j2];
      #pragma unroll
      for (int j2 = 0; j2 < 8; ++j2) Vt[scol + 8 + j2][srow] = v1[j2];
    }
    __syncthreads();

    // QK^T: S[16 q][64 kv] per wave
    f32x4 s[4];
    #pragma unroll
    for (int nt = 0; nt < 4; ++nt){
      f32x4 a0 = f32x4{0.f,0.f,0.f,0.f};
      #pragma unroll
      for (int ks = 0; ks < 2; ++ks){
        bf16x8 bf = *(const bf16x8*)&Ks[nt * 16 + la][ks * 32 + lg * 8];
        a0 = __builtin_amdgcn_mfma_f32_16x16x32_bf16(qf[ks], bf, a0, 0, 0, 0);
      }
      s[nt] = a0;
    }

    float pbuf[4][4];
    #pragma unroll
    for (int r = 0; r < 4; ++r){
      int qpos = qpb + r;
      float mx = -1e30f;
      #pragma unroll
      for (int nt = 0; nt < 4; ++nt){
        int kvpos = kv0 + nt * 16 + la;
        float sc = s[nt][r] + slope * (float)(kvpos - qpos);
        sc = (kvpos <= qpos) ? sc : -1e30f;
        pbuf[nt][r] = sc;
        mx = fmaxf(mx, sc);
      }
      mx = fmaxf(mx, __shfl_xor(mx, 1, 16));
      mx = fmaxf(mx, __shfl_xor(mx, 2, 16));
      mx = fmaxf(mx, __shfl_xor(mx, 4, 16));
      mx = fmaxf(mx, __shfl_xor(mx, 8, 16));
      float mnew = fmaxf(m_run[r], mx);
      float alpha = __expf(m_run[r] - mnew);
      m_run[r] = mnew;
      float ps = 0.f;
      #pragma unroll
      for (int nt = 0; nt < 4; ++nt){
        float p = __expf(pbuf[nt][r] - mnew);
        pbuf[nt][r] = p;
        ps += p;
      }
      ps += __shfl_xor(ps, 1, 16);
      ps += __shfl_xor(ps, 2, 16);
      ps += __shfl_xor(ps, 4, 16);
      ps += __shfl_xor(ps, 8, 16);
      l_run[r] = l_run[r] * alpha + ps;
      #pragma unroll
      for (int dt = 0; dt < 4; ++dt) o[dt][r] *= alpha;
    }

    #pragma unroll
    for (int r = 0; r < 4; ++r)
      #pragma unroll
      for (int nt = 0; nt < 4; ++nt)
        Ps[wave][lg * 4 + r][nt * 16 + la] = f2bf(pbuf[nt][r]);

    __syncthreads();

    // PV: O[16 q][64 d]
    #pragma unroll
    for (int ks = 0; ks < 2; ++ks){
      bf16x8 pa = *(const bf16x8*)&Ps[wave][la][ks * 32 + lg * 8];
      #pragma unroll
      for (int dt = 0; dt < 4; ++dt){
        bf16x8 bv = *(const bf16x8*)&Vt[dt * 16 + la][ks * 32 + lg * 8];
        o[dt] = __builtin_amdgcn_mfma_f32_16x16x32_bf16(pa, bv, o[dt], 0, 0, 0);
      }
    }
  }

  #pragma unroll
  for (int dt = 0; dt < 4; ++dt){
    #pragma unroll
    for (int r = 0; r < 4; ++r){
      int qpos = qpb + r;
      int d = dt * 16 + la;
      float val = o[dt][r] / l_run[r];
      concat[((size_t)(b * 2048 + qpos)) * 1024 + h * 64 + d] = f2bf(val);
    }
  }
}

extern "C" void kernel_launch(void* const* d_in, const int* in_sizes, int n_in,
                              void* d_out, int out_size, void* d_ws, size_t ws_size,
                              hipStream_t stream)
{
  (void)in_sizes; (void)n_in; (void)out_size; (void)ws_size;
  const float* x     = (const float*)d_in[0];
  const float* g1    = (const float*)d_in[1];
  const float* w_qkv = (const float*)d_in[2];
  const float* w_o   = (const float*)d_in[3];
  const float* g2    = (const float*)d_in[4];
  const float* W     = (const float*)d_in[5];
  const float* V     = (const float*)d_in[6];
  const float* W2    = (const float*)d_in[7];
  float* out = (float*)d_out;

  char* wsb = (char*)d_ws;
  size_t off = 0;
  auto alloc = [&](size_t bytes) -> void* {
    void* p = wsb + off;
    off += (bytes + 255) & ~(size_t)255;
    return p;
  };
  short* wqkvT = (short*)alloc((size_t)3072 * 1024 * 2); // [3C][C]
  short* woT   = (short*)alloc((size_t)1024 * 1024 * 2); // [C][C]
  short* WT    = (short*)alloc((size_t)2816 * 1024 * 2); // [Ppad][C], rows>=2728 zero
  short* VT    = (short*)alloc((size_t)2816 * 1024 * 2);
  short* W2T   = (short*)alloc((size_t)1024 * 2816 * 2); // [C][Ppad], cols>=2728 zero
  short* h1    = (short*)alloc((size_t)4096 * 1024 * 2);
  short* qbuf  = (short*)alloc((size_t)4096 * 1024 * 2); // [B,H,T,64]
  short* kbuf  = (short*)alloc((size_t)4096 * 1024 * 2);
  short* vbuf  = (short*)alloc((size_t)4096 * 1024 * 2);
  short* conc  = (short*)alloc((size_t)4096 * 1024 * 2);
  float* x2    = (float*)alloc((size_t)4096 * 1024 * 4);
  short* h2    = (short*)alloc((size_t)4096 * 1024 * 2);
  float* G     = (float*)alloc((size_t)4096 * 2816 * 4);
  short* gated = (short*)alloc((size_t)4096 * 2816 * 2);

  dim3 tb(32, 8);
  hipLaunchKernelGGL(transpose_bf16_kernel, dim3(96, 32), tb, 0, stream, w_qkv, wqkvT, 1024, 3072, 3072, 1024);
  hipLaunchKernelGGL(transpose_bf16_kernel, dim3(32, 32), tb, 0, stream, w_o,   woT,   1024, 1024, 1024, 1024);
  hipLaunchKernelGGL(transpose_bf16_kernel, dim3(88, 32), tb, 0, stream, W,     WT,    1024, 2728, 2816, 1024);
  hipLaunchKernelGGL(transpose_bf16_kernel, dim3(88, 32), tb, 0, stream, V,     VT,    1024, 2728, 2816, 1024);
  hipLaunchKernelGGL(transpose_bf16_kernel, dim3(32, 88), tb, 0, stream, W2,    W2T,   2728, 1024, 1024, 2816);

  hipLaunchKernelGGL(rmsnorm_kernel, dim3(4096), dim3(256), 0, stream, x, g1, h1);

  hipLaunchKernelGGL((gemm128_kernel<EPI_QKV>), dim3(32, 24), dim3(256), 0, stream,
                     h1, wqkvT, 4096, 3072, 1024,
                     (float*)nullptr, (short*)nullptr, (const float*)nullptr, (const float*)nullptr,
                     qbuf, kbuf, vbuf);

  hipLaunchKernelGGL(attn_kernel, dim3(32, 32), dim3(256), 0, stream, qbuf, kbuf, vbuf, conc);

  hipLaunchKernelGGL((gemm128_kernel<EPI_RESID>), dim3(32, 8), dim3(256), 0, stream,
                     conc, woT, 4096, 1024, 1024,
                     x2, (short*)nullptr, x, (const float*)nullptr,
                     (short*)nullptr, (short*)nullptr, (short*)nullptr);

  hipLaunchKernelGGL(rmsnorm_kernel, dim3(4096), dim3(256), 0, stream, x2, g2, h2);

  hipLaunchKernelGGL((gemm128_kernel<EPI_F32>), dim3(32, 22), dim3(256), 0, stream,
                     h2, WT, 4096, 2816, 1024,
                     G, (short*)nullptr, (const float*)nullptr, (const float*)nullptr,
                     (short*)nullptr, (short*)nullptr, (short*)nullptr);

  hipLaunchKernelGGL((gemm128_kernel<EPI_GATED>), dim3(32, 22), dim3(256), 0, stream,
                     h2, VT, 4096, 2816, 1024,
                     (float*)nullptr, gated, (const float*)nullptr, G,
                     (short*)nullptr, (short*)nullptr, (short*)nullptr);

  hipLaunchKernelGGL((gemm128_kernel<EPI_RESID>), dim3(32, 8), dim3(256), 0, stream,
                     gated, W2T, 4096, 1024, 2816,
                     out, (short*)nullptr, x2, (const float*)nullptr,
                     (short*)nullptr, (short*)nullptr, (short*)nullptr);
}

// Round 2
// 347.834 us; speedup vs baseline: 1.1469x; 1.1469x over previous
//
#include <hip/hip_runtime.h>
#include <math.h>

typedef __attribute__((ext_vector_type(8))) short bf16x8;
typedef __attribute__((ext_vector_type(4))) float f32x4;

static __device__ __forceinline__ short f2bf(float x){
  union { float f; unsigned u; } a; a.f = x;
  unsigned r = a.u + 0x7fffu + ((a.u >> 16) & 1u);
  return (short)(r >> 16);
}

// out[i][j] = (i < IC && j < IR) ? in[j][i] : 0 ; out dims [OR][OC] (bf16)
__global__ __launch_bounds__(256) void transpose_bf16_kernel(
    const float* __restrict__ in, short* __restrict__ out,
    int IR, int IC, int OR, int OC)
{
  __shared__ float tile[32][33];
  int i0 = blockIdx.x * 32;
  int j0 = blockIdx.y * 32;
  int tx = threadIdx.x, ty = threadIdx.y;
  #pragma unroll
  for (int r = 0; r < 32; r += 8){
    int j = j0 + ty + r, i = i0 + tx;
    tile[ty + r][tx] = (j < IR && i < IC) ? in[(size_t)j * IC + i] : 0.f;
  }
  __syncthreads();
  #pragma unroll
  for (int r = 0; r < 32; r += 8){
    int oi = i0 + ty + r, oj = j0 + tx;
    if (oi < OR && oj < OC) out[(size_t)oi * OC + oj] = f2bf(tile[tx][ty + r]);
  }
}

// one block per row of 1024; h = x / (sqrt(mean(x^2)) + eps) * g  -> bf16
__global__ __launch_bounds__(256) void rmsnorm_kernel(
    const float* __restrict__ x, const float* __restrict__ g, short* __restrict__ out)
{
  int row = blockIdx.x, tid = threadIdx.x;
  const float4* xr = (const float4*)(x + (size_t)row * 1024);
  float4 v = xr[tid];
  float ss = v.x*v.x + v.y*v.y + v.z*v.z + v.w*v.w;
  #pragma unroll
  for (int m = 1; m < 64; m <<= 1) ss += __shfl_xor(ss, m, 64);
  __shared__ float sm[4];
  if ((tid & 63) == 0) sm[tid >> 6] = ss;
  __syncthreads();
  float tot = sm[0] + sm[1] + sm[2] + sm[3];
  float inv = 1.f / (sqrtf(tot * (1.f/1024.f)) + 1e-5f);
  float4 gv = ((const float4*)g)[tid];
  short4 o;
  o.x = f2bf(v.x * inv * gv.x);
  o.y = f2bf(v.y * inv * gv.y);
  o.z = f2bf(v.z * inv * gv.z);
  o.w = f2bf(v.w * inv * gv.w);
  *(short4*)(out + (size_t)row * 1024 + tid * 4) = o;
}

enum { EPI_F32 = 0, EPI_RESID = 1, EPI_QKV = 2, EPI_GATED = 3 };

// C[M,N] = A[M,K](bf16,row-major) * Bt[N,K](bf16,row-major)^T ; 128x128 tile, 4 waves,
// global_load_lds width-16 staging (m97 structure). M%128==0, N%128==0, K%32==0.
template<int EPI>
__global__ __launch_bounds__(256) void gemm128_kernel(
    const short* __restrict__ A, const short* __restrict__ Bt,
    int M, int N, int K,
    float* __restrict__ outF, short* __restrict__ outB,
    const float* __restrict__ resid, const float* __restrict__ Gprev,
    short* __restrict__ qb, short* __restrict__ kb, short* __restrict__ vb)
{
  __shared__ short As[128 * 32];
  __shared__ short Bs[128 * 32];
  int tid = threadIdx.x, lane = tid & 63;
  int wave = tid >> 6, wr = wave >> 1, wc = wave & 1;
  int m0 = blockIdx.x * 128, n0 = blockIdx.y * 128;

  f32x4 acc[4][4];
  #pragma unroll
  for (int i = 0; i < 4; ++i)
    #pragma unroll
    for (int j = 0; j < 4; ++j) acc[i][j] = f32x4{0.f, 0.f, 0.f, 0.f};

  int off0 = tid * 16;          // byte offset in 8KB tile
  int off1 = off0 + 4096;
  int ar0 = off0 >> 6, ac0 = (off0 & 63) >> 1;
  int ar1 = off1 >> 6, ac1 = (off1 & 63) >> 1;
  const short* Ab = A + (size_t)m0 * K;
  const short* Bb = Bt + (size_t)n0 * K;
  int la = lane & 15, lb = (lane >> 4) * 8;

  for (int k0 = 0; k0 < K; k0 += 32){
    __syncthreads();
    __builtin_amdgcn_global_load_lds((const __attribute__((address_space(1))) void*)(Ab + (size_t)ar0 * K + k0 + ac0),
                                     (__attribute__((address_space(3))) void*)((char*)As + off0), 16, 0, 0);
    __builtin_amdgcn_global_load_lds((const __attribute__((address_space(1))) void*)(Ab + (size_t)ar1 * K + k0 + ac1),
                                     (__attribute__((address_space(3))) void*)((char*)As + off1), 16, 0, 0);
    __builtin_amdgcn_global_load_lds((const __attribute__((address_space(1))) void*)(Bb + (size_t)ar0 * K + k0 + ac0),
                                     (__attribute__((address_space(3))) void*)((char*)Bs + off0), 16, 0, 0);
    __builtin_amdgcn_global_load_lds((const __attribute__((address_space(1))) void*)(Bb + (size_t)ar1 * K + k0 + ac1),
                                     (__attribute__((address_space(3))) void*)((char*)Bs + off1), 16, 0, 0);
    __syncthreads();

    bf16x8 a[4], b[4];
    #pragma unroll
    for (int i = 0; i < 4; ++i)
      a[i] = *(const bf16x8*)(As + (wr * 64 + i * 16 + la) * 32 + lb);
    #pragma unroll
    for (int j = 0; j < 4; ++j)
      b[j] = *(const bf16x8*)(Bs + (wc * 64 + j * 16 + la) * 32 + lb);
    #pragma unroll
    for (int i = 0; i < 4; ++i)
      #pragma unroll
      for (int j = 0; j < 4; ++j)
        acc[i][j] = __builtin_amdgcn_mfma_f32_16x16x32_bf16(a[i], b[j], acc[i][j], 0, 0, 0);
  }

  int rbase = m0 + wr * 64 + (lane >> 4) * 4;
  int cbase = n0 + wc * 64 + la;
  #pragma unroll
  for (int i = 0; i < 4; ++i){
    #pragma unroll
    for (int j = 0; j < 4; ++j){
      #pragma unroll
      for (int r = 0; r < 4; ++r){
        int row = rbase + i * 16 + r;
        int col = cbase + j * 16;
        float v = acc[i][j][r];
        size_t idx = (size_t)row * N + col;
        if (EPI == EPI_F32){
          outF[idx] = v;
        } else if (EPI == EPI_RESID){
          outF[idx] = v + resid[idx];
        } else if (EPI == EPI_GATED){
          float gg = Gprev[idx];
          float s = gg / (1.f + __expf(-gg));
          outB[idx] = f2bf(s * v);
        } else { // EPI_QKV: scatter q,k -> [B,H,T,64]; v -> TRANSPOSED [B,H,64,T].
          int which = col >> 10;
          int hh = (col & 1023) >> 6;
          int d = col & 63;
          int bb = row >> 11, tt = row & 2047;
          if (which == 2){
            vb[((size_t)(bb * 16 + hh) * 64 + d) * 2048 + tt] = f2bf(v);
          } else {
            size_t o = (((size_t)(bb * 16 + hh) * 2048) + tt) * 64 + d;
            if (which == 0) qb[o] = f2bf(v * 0.03125f); // fold 1/sqrt(C)=1/32 into q
            else            kb[o] = f2bf(v);
          }
        }
      }
    }
  }
}

// flash attention, balanced: 8 waves x 16 q-rows = 128-row q-supertile; block p handles
// supertile p and 15-p (equal 34 kv-tile-iters). K/Vt double-buffered in LDS with
// register prefetch. V is pre-transposed in global: [bh][d][t]. q pre-scaled by 1/32.
__global__ __launch_bounds__(512) void attn_kernel(
    const short* __restrict__ qb, const short* __restrict__ kb,
    const short* __restrict__ vtb, short* __restrict__ concat)
{
  const int T = 2048;
  int bh = blockIdx.y;
  int h = bh & 15, b = bh >> 4;
  int p = blockIdx.x;
  int tid = threadIdx.x, lane = tid & 63, wave = tid >> 6;
  int la = lane & 15, lg = lane >> 4;

  const short* Q  = qb  + (size_t)bh * T * 64;
  const short* Kg = kb  + (size_t)bh * T * 64;  // [t][d]
  const short* Vt = vtb + (size_t)bh * 64 * T;  // [d][t]

  __shared__ short Ks[2][64][72];   // [buf][kv][d], pad 72 -> 2-way (free)
  __shared__ short Vs[2][64][72];   // [buf][d][kv]
  __shared__ short Ps[8][16][72];   // per-wave P tile

  int srow = tid >> 3, scol = (tid & 7) * 8;   // 64 rows x 8 chunks of 8 shorts
  float slope = exp2f(-0.5f * (float)(h + 1));

  for (int half = 0; half < 2; ++half){
    int j = half ? (15 - p) : p;
    int ntiles = 2 * j + 2;

    int qr = j * 128 + wave * 16 + la;
    bf16x8 qf0 = *(const bf16x8*)(Q + (size_t)qr * 64 + lg * 8);
    bf16x8 qf1 = *(const bf16x8*)(Q + (size_t)qr * 64 + 32 + lg * 8);

    f32x4 o[4];
    float m_run[4], l_run[4];
    #pragma unroll
    for (int i = 0; i < 4; ++i){ o[i] = f32x4{0.f,0.f,0.f,0.f}; m_run[i] = -1e30f; l_run[i] = 0.f; }

    // prologue: stage tile 0 into buf 0
    {
      bf16x8 k0 = *(const bf16x8*)(Kg + (size_t)srow * 64 + scol);
      bf16x8 v0 = *(const bf16x8*)(Vt + (size_t)srow * T + scol);
      *(bf16x8*)&Ks[0][srow][scol] = k0;
      *(bf16x8*)&Vs[0][srow][scol] = v0;
    }
    __syncthreads();

    int qpb = j * 128 + wave * 16 + lg * 4;

    for (int t = 0; t < ntiles; ++t){
      int cur = t & 1;
      int kv0 = t * 64;
      bool pref = (t + 1 < ntiles);
      bf16x8 kreg, vreg;
      if (pref){  // issue next-tile loads early; consumed after compute
        kreg = *(const bf16x8*)(Kg + (size_t)((t + 1) * 64 + srow) * 64 + scol);
        vreg = *(const bf16x8*)(Vt + (size_t)srow * T + (t + 1) * 64 + scol);
      }

      // QK^T: S[16 q][64 kv] per wave
      f32x4 s[4];
      #pragma unroll
      for (int nt = 0; nt < 4; ++nt){
        f32x4 a0 = f32x4{0.f,0.f,0.f,0.f};
        a0 = __builtin_amdgcn_mfma_f32_16x16x32_bf16(qf0, *(const bf16x8*)&Ks[cur][nt*16+la][lg*8],      a0, 0, 0, 0);
        a0 = __builtin_amdgcn_mfma_f32_16x16x32_bf16(qf1, *(const bf16x8*)&Ks[cur][nt*16+la][32+lg*8],   a0, 0, 0, 0);
        s[nt] = a0;
      }

      float pbuf[4][4];
      #pragma unroll
      for (int r = 0; r < 4; ++r){
        int qpos = qpb + r;
        float mx = -1e30f;
        #pragma unroll
        for (int nt = 0; nt < 4; ++nt){
          int kvpos = kv0 + nt * 16 + la;
          float sc = s[nt][r] + slope * (float)(kvpos - qpos);
          sc = (kvpos <= qpos) ? sc : -1e30f;
          pbuf[nt][r] = sc;
          mx = fmaxf(mx, sc);
        }
        mx = fmaxf(mx, __shfl_xor(mx, 1, 16));
        mx = fmaxf(mx, __shfl_xor(mx, 2, 16));
        mx = fmaxf(mx, __shfl_xor(mx, 4, 16));
        mx = fmaxf(mx, __shfl_xor(mx, 8, 16));
        float mnew = fmaxf(m_run[r], mx);
        float alpha = __expf(m_run[r] - mnew);
        m_run[r] = mnew;
        float ps = 0.f;
        #pragma unroll
        for (int nt = 0; nt < 4; ++nt){
          float pe = __expf(pbuf[nt][r] - mnew);
          pbuf[nt][r] = pe;
          ps += pe;
        }
        ps += __shfl_xor(ps, 1, 16);
        ps += __shfl_xor(ps, 2, 16);
        ps += __shfl_xor(ps, 4, 16);
        ps += __shfl_xor(ps, 8, 16);
        l_run[r] = l_run[r] * alpha + ps;
        #pragma unroll
        for (int dt = 0; dt < 4; ++dt) o[dt][r] *= alpha;
      }

      #pragma unroll
      for (int r = 0; r < 4; ++r)
        #pragma unroll
        for (int nt = 0; nt < 4; ++nt)
          Ps[wave][lg * 4 + r][nt * 16 + la] = f2bf(pbuf[nt][r]);

      // PV: O[16 q][64 d] (Ps write->read is intra-wave; lgkmcnt ordering suffices)
      #pragma unroll
      for (int ks = 0; ks < 2; ++ks){
        bf16x8 pa = *(const bf16x8*)&Ps[wave][la][ks * 32 + lg * 8];
        #pragma unroll
        for (int dt = 0; dt < 4; ++dt){
          bf16x8 bv = *(const bf16x8*)&Vs[cur][dt * 16 + la][ks * 32 + lg * 8];
          o[dt] = __builtin_amdgcn_mfma_f32_16x16x32_bf16(pa, bv, o[dt], 0, 0, 0);
        }
      }

      if (pref){  // write next tile into the other buffer (last read 2 tiles ago)
        *(bf16x8*)&Ks[cur ^ 1][srow][scol] = kreg;
        *(bf16x8*)&Vs[cur ^ 1][srow][scol] = vreg;
      }
      __syncthreads();
    }

    #pragma unroll
    for (int dt = 0; dt < 4; ++dt){
      #pragma unroll
      for (int r = 0; r < 4; ++r){
        int qpos = qpb + r;
        int d = dt * 16 + la;
        float val = o[dt][r] / l_run[r];
        concat[((size_t)(b * 2048 + qpos)) * 1024 + h * 64 + d] = f2bf(val);
      }
    }
  }
}

extern "C" void kernel_launch(void* const* d_in, const int* in_sizes, int n_in,
                              void* d_out, int out_size, void* d_ws, size_t ws_size,
                              hipStream_t stream)
{
  (void)in_sizes; (void)n_in; (void)out_size; (void)ws_size;
  const float* x     = (const float*)d_in[0];
  const float* g1    = (const float*)d_in[1];
  const float* w_qkv = (const float*)d_in[2];
  const float* w_o   = (const float*)d_in[3];
  const float* g2    = (const float*)d_in[4];
  const float* W     = (const float*)d_in[5];
  const float* V     = (const float*)d_in[6];
  const float* W2    = (const float*)d_in[7];
  float* out = (float*)d_out;

  char* wsb = (char*)d_ws;
  size_t off = 0;
  auto alloc = [&](size_t bytes) -> void* {
    void* p = wsb + off;
    off += (bytes + 255) & ~(size_t)255;
    return p;
  };
  short* wqkvT = (short*)alloc((size_t)3072 * 1024 * 2); // [3C][C]
  short* woT   = (short*)alloc((size_t)1024 * 1024 * 2); // [C][C]
  short* WT    = (short*)alloc((size_t)2816 * 1024 * 2); // [Ppad][C], rows>=2728 zero
  short* VT    = (short*)alloc((size_t)2816 * 1024 * 2);
  short* W2T   = (short*)alloc((size_t)1024 * 2816 * 2); // [C][Ppad], cols>=2728 zero
  short* h1    = (short*)alloc((size_t)4096 * 1024 * 2);
  short* qbuf  = (short*)alloc((size_t)4096 * 1024 * 2); // [B,H,T,64]
  short* kbuf  = (short*)alloc((size_t)4096 * 1024 * 2); // [B,H,T,64]
  short* vbuf  = (short*)alloc((size_t)4096 * 1024 * 2); // [B,H,64,T] (transposed)
  short* conc  = (short*)alloc((size_t)4096 * 1024 * 2);
  float* x2    = (float*)alloc((size_t)4096 * 1024 * 4);
  short* h2    = (short*)alloc((size_t)4096 * 1024 * 2);
  float* G     = (float*)alloc((size_t)4096 * 2816 * 4);
  short* gated = (short*)alloc((size_t)4096 * 2816 * 2);

  dim3 tb(32, 8);
  hipLaunchKernelGGL(transpose_bf16_kernel, dim3(96, 32), tb, 0, stream, w_qkv, wqkvT, 1024, 3072, 3072, 1024);
  hipLaunchKernelGGL(transpose_bf16_kernel, dim3(32, 32), tb, 0, stream, w_o,   woT,   1024, 1024, 1024, 1024);
  hipLaunchKernelGGL(transpose_bf16_kernel, dim3(88, 32), tb, 0, stream, W,     WT,    1024, 2728, 2816, 1024);
  hipLaunchKernelGGL(transpose_bf16_kernel, dim3(88, 32), tb, 0, stream, V,     VT,    1024, 2728, 2816, 1024);
  hipLaunchKernelGGL(transpose_bf16_kernel, dim3(32, 88), tb, 0, stream, W2,    W2T,   2728, 1024, 1024, 2816);

  hipLaunchKernelGGL(rmsnorm_kernel, dim3(4096), dim3(256), 0, stream, x, g1, h1);

  hipLaunchKernelGGL((gemm128_kernel<EPI_QKV>), dim3(32, 24), dim3(256), 0, stream,
                     h1, wqkvT, 4096, 3072, 1024,
                     (float*)nullptr, (short*)nullptr, (const float*)nullptr, (const float*)nullptr,
                     qbuf, kbuf, vbuf);

  hipLaunchKernelGGL(attn_kernel, dim3(8, 32), dim3(512), 0, stream, qbuf, kbuf, vbuf, conc);

  hipLaunchKernelGGL((gemm128_kernel<EPI_RESID>), dim3(32, 8), dim3(256), 0, stream,
                     conc, woT, 4096, 1024, 1024,
                     x2, (short*)nullptr, x, (const float*)nullptr,
                     (short*)nullptr, (short*)nullptr, (short*)nullptr);

  hipLaunchKernelGGL(rmsnorm_kernel, dim3(4096), dim3(256), 0, stream, x2, g2, h2);

  hipLaunchKernelGGL((gemm128_kernel<EPI_F32>), dim3(32, 22), dim3(256), 0, stream,
                     h2, WT, 4096, 2816, 1024,
                     G, (short*)nullptr, (const float*)nullptr, (const float*)nullptr,
                     (short*)nullptr, (short*)nullptr, (short*)nullptr);

  hipLaunchKernelGGL((gemm128_kernel<EPI_GATED>), dim3(32, 22), dim3(256), 0, stream,
                     h2, VT, 4096, 2816, 1024,
                     (float*)nullptr, gated, (const float*)nullptr, G,
                     (short*)nullptr, (short*)nullptr, (short*)nullptr);

  hipLaunchKernelGGL((gemm128_kernel<EPI_RESID>), dim3(32, 8), dim3(256), 0, stream,
                     gated, W2T, 4096, 1024, 2816,
                     out, (short*)nullptr, x2, (const float*)nullptr,
                     (short*)nullptr, (short*)nullptr, (short*)nullptr);
}

// Round 3
// 345.649 us; speedup vs baseline: 1.1542x; 1.0063x over previous
//
#include <hip/hip_runtime.h>
#include <math.h>

typedef __attribute__((ext_vector_type(8))) short bf16x8;
typedef __attribute__((ext_vector_type(4))) float f32x4;

static __device__ __forceinline__ short f2bf(float x){
  union { float f; unsigned u; } a; a.f = x;
  unsigned r = a.u + 0x7fffu + ((a.u >> 16) & 1u);
  return (short)(r >> 16);
}

// out[i][j] = (i < IC && j < IR) ? in[j][i] : 0 ; out dims [OR][OC] (bf16)
__global__ __launch_bounds__(256) void transpose_bf16_kernel(
    const float* __restrict__ in, short* __restrict__ out,
    int IR, int IC, int OR, int OC)
{
  __shared__ float tile[32][33];
  int i0 = blockIdx.x * 32;
  int j0 = blockIdx.y * 32;
  int tx = threadIdx.x, ty = threadIdx.y;
  #pragma unroll
  for (int r = 0; r < 32; r += 8){
    int j = j0 + ty + r, i = i0 + tx;
    tile[ty + r][tx] = (j < IR && i < IC) ? in[(size_t)j * IC + i] : 0.f;
  }
  __syncthreads();
  #pragma unroll
  for (int r = 0; r < 32; r += 8){
    int oi = i0 + ty + r, oj = j0 + tx;
    if (oi < OR && oj < OC) out[(size_t)oi * OC + oj] = f2bf(tile[tx][ty + r]);
  }
}

// one block per row of 1024; h = x / (sqrt(mean(x^2)) + eps) * g  -> bf16
__global__ __launch_bounds__(256) void rmsnorm_kernel(
    const float* __restrict__ x, const float* __restrict__ g, short* __restrict__ out)
{
  int row = blockIdx.x, tid = threadIdx.x;
  const float4* xr = (const float4*)(x + (size_t)row * 1024);
  float4 v = xr[tid];
  float ss = v.x*v.x + v.y*v.y + v.z*v.z + v.w*v.w;
  #pragma unroll
  for (int m = 1; m < 64; m <<= 1) ss += __shfl_xor(ss, m, 64);
  __shared__ float sm[4];
  if ((tid & 63) == 0) sm[tid >> 6] = ss;
  __syncthreads();
  float tot = sm[0] + sm[1] + sm[2] + sm[3];
  float inv = 1.f / (sqrtf(tot * (1.f/1024.f)) + 1e-5f);
  float4 gv = ((const float4*)g)[tid];
  short4 o;
  o.x = f2bf(v.x * inv * gv.x);
  o.y = f2bf(v.y * inv * gv.y);
  o.z = f2bf(v.z * inv * gv.z);
  o.w = f2bf(v.w * inv * gv.w);
  *(short4*)(out + (size_t)row * 1024 + tid * 4) = o;
}

enum { EPI_F32 = 0, EPI_RESID = 1, EPI_QKV = 2, EPI_GATED = 3 };

// ---------------- 128x128 m97-structure GEMM (kept for N=1024 shapes) -------
template<int EPI>
__global__ __launch_bounds__(256) void gemm128_kernel(
    const short* __restrict__ A, const short* __restrict__ Bt,
    int M, int N, int K,
    float* __restrict__ outF, short* __restrict__ outB,
    const float* __restrict__ resid, const float* __restrict__ Gprev,
    short* __restrict__ qb, short* __restrict__ kb, short* __restrict__ vb)
{
  __shared__ short As[128 * 32];
  __shared__ short Bs[128 * 32];
  int tid = threadIdx.x, lane = tid & 63;
  int wave = tid >> 6, wr = wave >> 1, wc = wave & 1;
  int m0 = blockIdx.x * 128, n0 = blockIdx.y * 128;

  f32x4 acc[4][4];
  #pragma unroll
  for (int i = 0; i < 4; ++i)
    #pragma unroll
    for (int j = 0; j < 4; ++j) acc[i][j] = f32x4{0.f, 0.f, 0.f, 0.f};

  int off0 = tid * 16;
  int off1 = off0 + 4096;
  int ar0 = off0 >> 6, ac0 = (off0 & 63) >> 1;
  int ar1 = off1 >> 6, ac1 = (off1 & 63) >> 1;
  const short* Ab = A + (size_t)m0 * K;
  const short* Bb = Bt + (size_t)n0 * K;
  int la = lane & 15, lb = (lane >> 4) * 8;

  for (int k0 = 0; k0 < K; k0 += 32){
    __syncthreads();
    __builtin_amdgcn_global_load_lds((const __attribute__((address_space(1))) void*)(Ab + (size_t)ar0 * K + k0 + ac0),
                                     (__attribute__((address_space(3))) void*)((char*)As + off0), 16, 0, 0);
    __builtin_amdgcn_global_load_lds((const __attribute__((address_space(1))) void*)(Ab + (size_t)ar1 * K + k0 + ac1),
                                     (__attribute__((address_space(3))) void*)((char*)As + off1), 16, 0, 0);
    __builtin_amdgcn_global_load_lds((const __attribute__((address_space(1))) void*)(Bb + (size_t)ar0 * K + k0 + ac0),
                                     (__attribute__((address_space(3))) void*)((char*)Bs + off0), 16, 0, 0);
    __builtin_amdgcn_global_load_lds((const __attribute__((address_space(1))) void*)(Bb + (size_t)ar1 * K + k0 + ac1),
                                     (__attribute__((address_space(3))) void*)((char*)Bs + off1), 16, 0, 0);
    __syncthreads();

    bf16x8 a[4], b[4];
    #pragma unroll
    for (int i = 0; i < 4; ++i)
      a[i] = *(const bf16x8*)(As + (wr * 64 + i * 16 + la) * 32 + lb);
    #pragma unroll
    for (int j = 0; j < 4; ++j)
      b[j] = *(const bf16x8*)(Bs + (wc * 64 + j * 16 + la) * 32 + lb);
    #pragma unroll
    for (int i = 0; i < 4; ++i)
      #pragma unroll
      for (int j = 0; j < 4; ++j)
        acc[i][j] = __builtin_amdgcn_mfma_f32_16x16x32_bf16(a[i], b[j], acc[i][j], 0, 0, 0);
  }

  int rbase = m0 + wr * 64 + (lane >> 4) * 4;
  int cbase = n0 + wc * 64 + la;
  #pragma unroll
  for (int i = 0; i < 4; ++i){
    #pragma unroll
    for (int j = 0; j < 4; ++j){
      #pragma unroll
      for (int r = 0; r < 4; ++r){
        int row = rbase + i * 16 + r;
        int col = cbase + j * 16;
        float v = acc[i][j][r];
        size_t idx = (size_t)row * N + col;
        if (EPI == EPI_F32){
          outF[idx] = v;
        } else if (EPI == EPI_RESID){
          outF[idx] = v + resid[idx];
        } else if (EPI == EPI_GATED){
          float gg = Gprev[idx];
          float s = gg / (1.f + __expf(-gg));
          outB[idx] = f2bf(s * v);
        } else {
          int which = col >> 10;
          int hh = (col & 1023) >> 6;
          int d = col & 63;
          int bb = row >> 11, tt = row & 2047;
          if (which == 2){
            vb[((size_t)(bb * 16 + hh) * 64 + d) * 2048 + tt] = f2bf(v);
          } else {
            size_t o = (((size_t)(bb * 16 + hh) * 2048) + tt) * 64 + d;
            if (which == 0) qb[o] = f2bf(v * 0.03125f);
            else            kb[o] = f2bf(v);
          }
        }
      }
    }
  }
}

// ---------------- 256x256 8-wave counted-vmcnt GEMM ------------------------
// A[M,K] bf16 row-major, Bt[N,K] bf16 row-major (B transposed). M,N %256==0, K%64==0.
// 8 waves = 2M x 4N; per-wave C = 128x64. LDS: 2 K-tile buffers x (A 32KB + B 32KB).
// Swizzle: LDS phys 16B-chunk (r, cp) holds logical (r, cp ^ (r&7)).
// Per-wave staging of exactly the half-tiles it reads, issue order
// [A-rh0 x2, B-ch0 x2, B-ch1 x2, A-rh1 x2] -> all steady-state waits = vmcnt(4).

static __device__ __forceinline__ void g256_issue(
    const short* __restrict__ A, const short* __restrict__ Bt,
    short* lb, int K, int m0, int n0, int k0,
    int wr, int wc, int lane, int l)
{
  int wbq = wr * 2 + (wc & 1);
  int region, rowbase;
  if (l < 2)      { region = wr;          rowbase = wc * 16 + l * 8; }
  else if (l < 4) { region = 2 + (wc>>1); rowbase = (wbq>>1)*64 + (wbq&1)*16 + (l-2)*8; }
  else if (l < 6) { region = 2 + (wc>>1); rowbase = 32 + (wbq>>1)*64 + (wbq&1)*16 + (l-4)*8; }
  else            { region = wr;          rowbase = 64 + wc * 16 + (l-6)*8; }
  int rloc = rowbase + (lane >> 3);
  int c16l = (lane & 7) ^ (rloc & 7);
  const short* src;
  if (region < 2) src = A  + (size_t)(m0 + region * 128 + rloc) * K + k0 + c16l * 8;
  else            src = Bt + (size_t)(n0 + (region - 2) * 128 + rloc) * K + k0 + c16l * 8;
  short* dst = lb + region * 8192 + rowbase * 64 + lane * 8;
  __builtin_amdgcn_global_load_lds((const __attribute__((address_space(1))) void*)src,
                                   (__attribute__((address_space(3))) void*)dst, 16, 0, 0);
}

template<int EPI>
__global__ __launch_bounds__(512, 2) void gemm256_kernel(
    const short* __restrict__ A, const short* __restrict__ Bt,
    int M, int N, int K,
    float* __restrict__ outF, short* __restrict__ outB,
    const float* __restrict__ Gprev,
    short* __restrict__ qb, short* __restrict__ kb, short* __restrict__ vb)
{
  __shared__ short lds[2][4][8192];
  const int tid = threadIdx.x, lane = tid & 63, wave = tid >> 6;
  const int wr = wave >> 2, wc = wave & 3;
  const int la = lane & 15, lg = lane >> 4;

  int nbn = N >> 8;
  int nwg = (M >> 8) * nbn;
  int bid = blockIdx.x;
  int wg = ((nwg & 7) == 0) ? ((bid & 7) * (nwg >> 3) + (bid >> 3)) : bid;  // XCD swizzle
  int m0 = (wg / nbn) << 8, n0 = (wg % nbn) << 8;

  f32x4 acc[8][4];
  #pragma unroll
  for (int i = 0; i < 8; ++i)
    #pragma unroll
    for (int j = 0; j < 4; ++j) acc[i][j] = f32x4{0.f, 0.f, 0.f, 0.f};

  // prologue: tile 0 into buf 0
  #pragma unroll
  for (int l = 0; l < 8; ++l)
    g256_issue(A, Bt, &lds[0][0][0], K, m0, n0, 0, wr, wc, lane, l);

  const int NT = K >> 6;

#define GPHASE(RH, CH, L0)                                                       \
  do {                                                                           \
    bf16x8 af[4][2], bf[2][2];                                                   \
    _Pragma("unroll")                                                            \
    for (int ii = 0; ii < 4; ++ii){                                              \
      int r = (RH) * 64 + ii * 16 + la;                                          \
      _Pragma("unroll")                                                          \
      for (int ks = 0; ks < 2; ++ks)                                             \
        af[ii][ks] = *(const bf16x8*)(curb + wr * 8192 + r * 64 +                \
                                      (((ks * 4 + lg) ^ (r & 7)) * 8));          \
    }                                                                            \
    _Pragma("unroll")                                                            \
    for (int jc = 0; jc < 2; ++jc){                                              \
      int rb = (wc & 1) * 64 + ((CH) * 2 + jc) * 16 + la;                        \
      _Pragma("unroll")                                                          \
      for (int ks = 0; ks < 2; ++ks)                                             \
        bf[jc][ks] = *(const bf16x8*)(curb + (2 + (wc >> 1)) * 8192 + rb * 64 +  \
                                      (((ks * 4 + lg) ^ (rb & 7)) * 8));         \
    }                                                                            \
    if (pf){                                                                     \
      g256_issue(A, Bt, nxtb, K, m0, n0, k1, wr, wc, lane, (L0));                \
      g256_issue(A, Bt, nxtb, K, m0, n0, k1, wr, wc, lane, (L0) + 1);            \
    }                                                                            \
    __builtin_amdgcn_s_setprio(1);                                               \
    _Pragma("unroll")                                                            \
    for (int ii = 0; ii < 4; ++ii)                                               \
      _Pragma("unroll")                                                          \
      for (int jc = 0; jc < 2; ++jc){                                            \
        acc[(RH)*4+ii][(CH)*2+jc] = __builtin_amdgcn_mfma_f32_16x16x32_bf16(     \
            af[ii][0], bf[jc][0], acc[(RH)*4+ii][(CH)*2+jc], 0, 0, 0);           \
        acc[(RH)*4+ii][(CH)*2+jc] = __builtin_amdgcn_mfma_f32_16x16x32_bf16(     \
            af[ii][1], bf[jc][1], acc[(RH)*4+ii][(CH)*2+jc], 0, 0, 0);           \
      }                                                                          \
    __builtin_amdgcn_s_setprio(0);                                               \
  } while (0)

  for (int t = 0; t < NT; ++t){
    short* curb = &lds[t & 1][0][0];
    short* nxtb = &lds[(t + 1) & 1][0][0];
    const bool pf = (t + 1 < NT);
    const int k1 = (t + 1) << 6;

    // W0: need tile t's loads 0-3 (A-rh0, B-ch0); leave 4 youngest in flight
    asm volatile("s_waitcnt vmcnt(4)" ::: "memory");
    __builtin_amdgcn_s_barrier();
    __builtin_amdgcn_sched_barrier(0);
    GPHASE(0, 0, 0);

    // W1: need loads 4-5 (B-ch1)
    if (pf) asm volatile("s_waitcnt vmcnt(4)" ::: "memory");
    else    asm volatile("s_waitcnt vmcnt(2)" ::: "memory");
    __builtin_amdgcn_s_barrier();
    __builtin_amdgcn_sched_barrier(0);
    GPHASE(0, 1, 2);

    // W2: need loads 6-7 (A-rh1)
    if (pf) asm volatile("s_waitcnt vmcnt(4)" ::: "memory");
    else    asm volatile("s_waitcnt vmcnt(0)" ::: "memory");
    __builtin_amdgcn_s_barrier();
    __builtin_amdgcn_sched_barrier(0);
    GPHASE(1, 0, 4);
    GPHASE(1, 1, 6);
  }
#undef GPHASE

  #pragma unroll
  for (int i = 0; i < 8; ++i){
    #pragma unroll
    for (int j = 0; j < 4; ++j){
      #pragma unroll
      for (int rr = 0; rr < 4; ++rr){
        int row = m0 + wr * 128 + i * 16 + lg * 4 + rr;
        int col = n0 + wc * 64 + j * 16 + la;
        float v = acc[i][j][rr];
        size_t idx = (size_t)row * N + col;
        if (EPI == EPI_F32){
          outF[idx] = v;
        } else if (EPI == EPI_GATED){
          float gg = Gprev[idx];
          float s = gg / (1.f + __expf(-gg));
          outB[idx] = f2bf(s * v);
        } else if (EPI == EPI_QKV){
          int which = col >> 10;
          int hh = (col & 1023) >> 6;
          int d = col & 63;
          int bb = row >> 11, tt = row & 2047;
          if (which == 2){
            vb[((size_t)(bb * 16 + hh) * 64 + d) * 2048 + tt] = f2bf(v);
          } else {
            size_t o = (((size_t)(bb * 16 + hh) * 2048) + tt) * 64 + d;
            if (which == 0) qb[o] = f2bf(v * 0.03125f);
            else            kb[o] = f2bf(v);
          }
        }
      }
    }
  }
}

// ---------------- flash attention (unchanged from round 2) -----------------
__global__ __launch_bounds__(512) void attn_kernel(
    const short* __restrict__ qb, const short* __restrict__ kb,
    const short* __restrict__ vtb, short* __restrict__ concat)
{
  const int T = 2048;
  int bh = blockIdx.y;
  int h = bh & 15, b = bh >> 4;
  int p = blockIdx.x;
  int tid = threadIdx.x, lane = tid & 63, wave = tid >> 6;
  int la = lane & 15, lg = lane >> 4;

  const short* Q  = qb  + (size_t)bh * T * 64;
  const short* Kg = kb  + (size_t)bh * T * 64;
  const short* Vt = vtb + (size_t)bh * 64 * T;

  __shared__ short Ks[2][64][72];
  __shared__ short Vs[2][64][72];
  __shared__ short Ps[8][16][72];

  int srow = tid >> 3, scol = (tid & 7) * 8;
  float slope = exp2f(-0.5f * (float)(h + 1));

  for (int half = 0; half < 2; ++half){
    int j = half ? (15 - p) : p;
    int ntiles = 2 * j + 2;

    int qr = j * 128 + wave * 16 + la;
    bf16x8 qf0 = *(const bf16x8*)(Q + (size_t)qr * 64 + lg * 8);
    bf16x8 qf1 = *(const bf16x8*)(Q + (size_t)qr * 64 + 32 + lg * 8);

    f32x4 o[4];
    float m_run[4], l_run[4];
    #pragma unroll
    for (int i = 0; i < 4; ++i){ o[i] = f32x4{0.f,0.f,0.f,0.f}; m_run[i] = -1e30f; l_run[i] = 0.f; }

    {
      bf16x8 k0 = *(const bf16x8*)(Kg + (size_t)srow * 64 + scol);
      bf16x8 v0 = *(const bf16x8*)(Vt + (size_t)srow * T + scol);
      *(bf16x8*)&Ks[0][srow][scol] = k0;
      *(bf16x8*)&Vs[0][srow][scol] = v0;
    }
    __syncthreads();

    int qpb = j * 128 + wave * 16 + lg * 4;

    for (int t = 0; t < ntiles; ++t){
      int cur = t & 1;
      int kv0 = t * 64;
      bool pref = (t + 1 < ntiles);
      bf16x8 kreg, vreg;
      if (pref){
        kreg = *(const bf16x8*)(Kg + (size_t)((t + 1) * 64 + srow) * 64 + scol);
        vreg = *(const bf16x8*)(Vt + (size_t)srow * T + (t + 1) * 64 + scol);
      }

      f32x4 s[4];
      #pragma unroll
      for (int nt = 0; nt < 4; ++nt){
        f32x4 a0 = f32x4{0.f,0.f,0.f,0.f};
        a0 = __builtin_amdgcn_mfma_f32_16x16x32_bf16(qf0, *(const bf16x8*)&Ks[cur][nt*16+la][lg*8],    a0, 0, 0, 0);
        a0 = __builtin_amdgcn_mfma_f32_16x16x32_bf16(qf1, *(const bf16x8*)&Ks[cur][nt*16+la][32+lg*8], a0, 0, 0, 0);
        s[nt] = a0;
      }

      float pbuf[4][4];
      #pragma unroll
      for (int r = 0; r < 4; ++r){
        int qpos = qpb + r;
        float mx = -1e30f;
        #pragma unroll
        for (int nt = 0; nt < 4; ++nt){
          int kvpos = kv0 + nt * 16 + la;
          float sc = s[nt][r] + slope * (float)(kvpos - qpos);
          sc = (kvpos <= qpos) ? sc : -1e30f;
          pbuf[nt][r] = sc;
          mx = fmaxf(mx, sc);
        }
        mx = fmaxf(mx, __shfl_xor(mx, 1, 16));
        mx = fmaxf(mx, __shfl_xor(mx, 2, 16));
        mx = fmaxf(mx, __shfl_xor(mx, 4, 16));
        mx = fmaxf(mx, __shfl_xor(mx, 8, 16));
        float mnew = fmaxf(m_run[r], mx);
        float alpha = __expf(m_run[r] - mnew);
        m_run[r] = mnew;
        float ps = 0.f;
        #pragma unroll
        for (int nt = 0; nt < 4; ++nt){
          float pe = __expf(pbuf[nt][r] - mnew);
          pbuf[nt][r] = pe;
          ps += pe;
        }
        ps += __shfl_xor(ps, 1, 16);
        ps += __shfl_xor(ps, 2, 16);
        ps += __shfl_xor(ps, 4, 16);
        ps += __shfl_xor(ps, 8, 16);
        l_run[r] = l_run[r] * alpha + ps;
        #pragma unroll
        for (int dt = 0; dt < 4; ++dt) o[dt][r] *= alpha;
      }

      #pragma unroll
      for (int r = 0; r < 4; ++r)
        #pragma unroll
        for (int nt = 0; nt < 4; ++nt)
          Ps[wave][lg * 4 + r][nt * 16 + la] = f2bf(pbuf[nt][r]);

      #pragma unroll
      for (int ks = 0; ks < 2; ++ks){
        bf16x8 pa = *(const bf16x8*)&Ps[wave][la][ks * 32 + lg * 8];
        #pragma unroll
        for (int dt = 0; dt < 4; ++dt){
          bf16x8 bv = *(const bf16x8*)&Vs[cur][dt * 16 + la][ks * 32 + lg * 8];
          o[dt] = __builtin_amdgcn_mfma_f32_16x16x32_bf16(pa, bv, o[dt], 0, 0, 0);
        }
      }

      if (pref){
        *(bf16x8*)&Ks[cur ^ 1][srow][scol] = kreg;
        *(bf16x8*)&Vs[cur ^ 1][srow][scol] = vreg;
      }
      __syncthreads();
    }

    #pragma unroll
    for (int dt = 0; dt < 4; ++dt){
      #pragma unroll
      for (int r = 0; r < 4; ++r){
        int qpos = qpb + r;
        int d = dt * 16 + la;
        float val = o[dt][r] / l_run[r];
        concat[((size_t)(b * 2048 + qpos)) * 1024 + h * 64 + d] = f2bf(val);
      }
    }
  }
}

extern "C" void kernel_launch(void* const* d_in, const int* in_sizes, int n_in,
                              void* d_out, int out_size, void* d_ws, size_t ws_size,
                              hipStream_t stream)
{
  (void)in_sizes; (void)n_in; (void)out_size; (void)ws_size;
  const float* x     = (const float*)d_in[0];
  const float* g1    = (const float*)d_in[1];
  const float* w_qkv = (const float*)d_in[2];
  const float* w_o   = (const float*)d_in[3];
  const float* g2    = (const float*)d_in[4];
  const float* W     = (const float*)d_in[5];
  const float* V     = (const float*)d_in[6];
  const float* W2    = (const float*)d_in[7];
  float* out = (float*)d_out;

  char* wsb = (char*)d_ws;
  size_t off = 0;
  auto alloc = [&](size_t bytes) -> void* {
    void* p = wsb + off;
    off += (bytes + 255) & ~(size_t)255;
    return p;
  };
  short* wqkvT = (short*)alloc((size_t)3072 * 1024 * 2);
  short* woT   = (short*)alloc((size_t)1024 * 1024 * 2);
  short* WT    = (short*)alloc((size_t)2816 * 1024 * 2);
  short* VT    = (short*)alloc((size_t)2816 * 1024 * 2);
  short* W2T   = (short*)alloc((size_t)1024 * 2816 * 2);
  short* h1    = (short*)alloc((size_t)4096 * 1024 * 2);
  short* qbuf  = (short*)alloc((size_t)4096 * 1024 * 2);
  short* kbuf  = (short*)alloc((size_t)4096 * 1024 * 2);
  short* vbuf  = (short*)alloc((size_t)4096 * 1024 * 2);
  short* conc  = (short*)alloc((size_t)4096 * 1024 * 2);
  float* x2    = (float*)alloc((size_t)4096 * 1024 * 4);
  short* h2    = (short*)alloc((size_t)4096 * 1024 * 2);
  float* G     = (float*)alloc((size_t)4096 * 2816 * 4);
  short* gated = (short*)alloc((size_t)4096 * 2816 * 2);

  dim3 tb(32, 8);
  hipLaunchKernelGGL(transpose_bf16_kernel, dim3(96, 32), tb, 0, stream, w_qkv, wqkvT, 1024, 3072, 3072, 1024);
  hipLaunchKernelGGL(transpose_bf16_kernel, dim3(32, 32), tb, 0, stream, w_o,   woT,   1024, 1024, 1024, 1024);
  hipLaunchKernelGGL(transpose_bf16_kernel, dim3(88, 32), tb, 0, stream, W,     WT,    1024, 2728, 2816, 1024);
  hipLaunchKernelGGL(transpose_bf16_kernel, dim3(88, 32), tb, 0, stream, V,     VT,    1024, 2728, 2816, 1024);
  hipLaunchKernelGGL(transpose_bf16_kernel, dim3(32, 88), tb, 0, stream, W2,    W2T,   2728, 1024, 1024, 2816);

  hipLaunchKernelGGL(rmsnorm_kernel, dim3(4096), dim3(256), 0, stream, x, g1, h1);

  // QKV: 4096 x 3072 x 1024 on the 256^2 8-wave kernel (192 blocks)
  hipLaunchKernelGGL((gemm256_kernel<EPI_QKV>), dim3(16 * 12), dim3(512), 0, stream,
                     h1, wqkvT, 4096, 3072, 1024,
                     (float*)nullptr, (short*)nullptr, (const float*)nullptr,
                     qbuf, kbuf, vbuf);

  hipLaunchKernelGGL(attn_kernel, dim3(8, 32), dim3(512), 0, stream, qbuf, kbuf, vbuf, conc);

  hipLaunchKernelGGL((gemm128_kernel<EPI_RESID>), dim3(32, 8), dim3(256), 0, stream,
                     conc, woT, 4096, 1024, 1024,
                     x2, (short*)nullptr, x, (const float*)nullptr,
                     (short*)nullptr, (short*)nullptr, (short*)nullptr);

  hipLaunchKernelGGL(rmsnorm_kernel, dim3(4096), dim3(256), 0, stream, x2, g2, h2);

  // W: 4096 x 2816 x 1024 (176 blocks)
  hipLaunchKernelGGL((gemm256_kernel<EPI_F32>), dim3(16 * 11), dim3(512), 0, stream,
                     h2, WT, 4096, 2816, 1024,
                     G, (short*)nullptr, (const float*)nullptr,
                     (short*)nullptr, (short*)nullptr, (short*)nullptr);

  // V: 4096 x 2816 x 1024, gated epilogue (176 blocks)
  hipLaunchKernelGGL((gemm256_kernel<EPI_GATED>), dim3(16 * 11), dim3(512), 0, stream,
                     h2, VT, 4096, 2816, 1024,
                     (float*)nullptr, gated, G,
                     (short*)nullptr, (short*)nullptr, (short*)nullptr);

  hipLaunchKernelGGL((gemm128_kernel<EPI_RESID>), dim3(32, 8), dim3(256), 0, stream,
                     gated, W2T, 4096, 1024, 2816,
                     out, (short*)nullptr, x2, (const float*)nullptr,
                     (short*)nullptr, (short*)nullptr, (short*)nullptr);
}

// Round 4
// 299.424 us; speedup vs baseline: 1.3324x; 1.1544x over previous
//
#include <hip/hip_runtime.h>
#include <math.h>

typedef __attribute__((ext_vector_type(8))) short bf16x8;
typedef __attribute__((ext_vector_type(4))) float f32x4;

static __device__ __forceinline__ short f2bf(float x){
  union { float f; unsigned u; } a; a.f = x;
  unsigned r = a.u + 0x7fffu + ((a.u >> 16) & 1u);
  return (short)(r >> 16);
}

// out[i][j] = (i < IC && j < IR) ? in[j][i] : 0 ; out dims [OR][OC] (bf16)
__global__ __launch_bounds__(256) void transpose_bf16_kernel(
    const float* __restrict__ in, short* __restrict__ out,
    int IR, int IC, int OR, int OC)
{
  __shared__ float tile[32][33];
  int i0 = blockIdx.x * 32;
  int j0 = blockIdx.y * 32;
  int tx = threadIdx.x, ty = threadIdx.y;
  #pragma unroll
  for (int r = 0; r < 32; r += 8){
    int j = j0 + ty + r, i = i0 + tx;
    tile[ty + r][tx] = (j < IR && i < IC) ? in[(size_t)j * IC + i] : 0.f;
  }
  __syncthreads();
  #pragma unroll
  for (int r = 0; r < 32; r += 8){
    int oi = i0 + ty + r, oj = j0 + tx;
    if (oi < OR && oj < OC) out[(size_t)oi * OC + oj] = f2bf(tile[tx][ty + r]);
  }
}

// bf16 transpose: in [32 bh][2048][64] -> out [32 bh][64][2048]
__global__ __launch_bounds__(256) void transpose_bb_kernel(
    const short* __restrict__ in, short* __restrict__ out)
{
  __shared__ short tile[32][33];
  int bh = blockIdx.z;
  int t0 = blockIdx.x * 32;
  int d0 = blockIdx.y * 32;
  int tx = threadIdx.x, ty = threadIdx.y;
  const short* src = in + ((size_t)bh * 2048 + t0) * 64 + d0;
  #pragma unroll
  for (int r = 0; r < 32; r += 8)
    tile[ty + r][tx] = src[(size_t)(ty + r) * 64 + tx];
  __syncthreads();
  short* dst = out + ((size_t)bh * 64 + d0) * 2048 + t0;
  #pragma unroll
  for (int r = 0; r < 32; r += 8)
    dst[(size_t)(ty + r) * 2048 + tx] = tile[tx][ty + r];
}

// one block per row of 1024; h = x / (sqrt(mean(x^2)) + eps) * g  -> bf16
__global__ __launch_bounds__(256) void rmsnorm_kernel(
    const float* __restrict__ x, const float* __restrict__ g, short* __restrict__ out)
{
  int row = blockIdx.x, tid = threadIdx.x;
  const float4* xr = (const float4*)(x + (size_t)row * 1024);
  float4 v = xr[tid];
  float ss = v.x*v.x + v.y*v.y + v.z*v.z + v.w*v.w;
  #pragma unroll
  for (int m = 1; m < 64; m <<= 1) ss += __shfl_xor(ss, m, 64);
  __shared__ float sm[4];
  if ((tid & 63) == 0) sm[tid >> 6] = ss;
  __syncthreads();
  float tot = sm[0] + sm[1] + sm[2] + sm[3];
  float inv = 1.f / (sqrtf(tot * (1.f/1024.f)) + 1e-5f);
  float4 gv = ((const float4*)g)[tid];
  short4 o;
  o.x = f2bf(v.x * inv * gv.x);
  o.y = f2bf(v.y * inv * gv.y);
  o.z = f2bf(v.z * inv * gv.z);
  o.w = f2bf(v.w * inv * gv.w);
  *(short4*)(out + (size_t)row * 1024 + tid * 4) = o;
}

enum { EPI_F32 = 0, EPI_RESID = 1, EPI_QKV = 2, EPI_GATED = 3 };

// ---------------- deep-pipeline GEMM template ------------------------------
// C[M,N] = A[M,K] * Bt[N,K]^T, bf16 in, fp32 acc. BK=64, 8 waves (2Mx4N).
// Per K-tile: wait vmcnt(L); barrier; 64(or 16) MFMA + ds_reads; barrier;
// issue tile t+2 into the just-freed buffer. Loads live a full K-tile.
// LDS layout: A region then B region, row-major 64-short rows; 16B chunk p of
// row r holds logical chunk p^(r&7) (XOR swizzle via pre-swizzled global src).

template<int BM, int BN>
static __device__ __forceinline__ void dp_issue(
    const short* __restrict__ A, const short* __restrict__ Bt,
    short* __restrict__ lbuf, int K, int m0, int n0, int k0,
    int wave, int lane, int l)
{
  int g = (l * 8 + wave) * 64 + lane;
  const short* src;
  if (g < BM * 8){
    int row = g >> 3, cc = g & 7;
    src = A + (size_t)(m0 + row) * K + k0 + ((cc ^ (row & 7)) << 3);
  } else {
    int gb = g - BM * 8;
    int row = gb >> 3, cc = gb & 7;
    src = Bt + (size_t)(n0 + row) * K + k0 + ((cc ^ (row & 7)) << 3);
  }
  __builtin_amdgcn_global_load_lds((const __attribute__((address_space(1))) void*)src,
                                   (__attribute__((address_space(3))) void*)(lbuf + (size_t)g * 8),
                                   16, 0, 0);
}

template<int BM, int BN, int EPI>
__global__ __launch_bounds__(512, 2) void gemm_dp_kernel(
    const short* __restrict__ A, const short* __restrict__ Bt,
    int M, int N, int K,
    float* __restrict__ outF, short* __restrict__ outB,
    const float* __restrict__ resid, const float* __restrict__ Gprev,
    short* __restrict__ qb, short* __restrict__ kb, short* __restrict__ vb)
{
  constexpr int L  = (BM + BN) / 64;   // loads per wave per K-tile
  constexpr int WM = BM / 2, WN = BN / 4;
  constexpr int FR = WM / 16, FC = WN / 16;
  __shared__ short lds[2][(BM + BN) * 64];
  const int tid = threadIdx.x, lane = tid & 63, wave = tid >> 6;
  const int wr = wave >> 2, wc = wave & 3;
  const int la = lane & 15, lg = lane >> 4;

  int nbn = N / BN;
  int nwg = (M / BM) * nbn;
  int bid = blockIdx.x;
  int wg = ((nwg & 7) == 0) ? ((bid & 7) * (nwg >> 3) + (bid >> 3)) : bid;  // XCD swizzle
  int m0 = (wg / nbn) * BM, n0 = (wg % nbn) * BN;

  f32x4 acc[FR][FC];
  #pragma unroll
  for (int i = 0; i < FR; ++i)
    #pragma unroll
    for (int j = 0; j < FC; ++j) acc[i][j] = f32x4{0.f, 0.f, 0.f, 0.f};

  const int NT = K >> 6;

  // prologue: tiles 0 and 1
  #pragma unroll
  for (int l = 0; l < L; ++l) dp_issue<BM, BN>(A, Bt, lds[0], K, m0, n0, 0,  wave, lane, l);
  #pragma unroll
  for (int l = 0; l < L; ++l) dp_issue<BM, BN>(A, Bt, lds[1], K, m0, n0, 64, wave, lane, l);

  for (int t = 0; t < NT; ++t){
    short* curb = lds[t & 1];
    if (t + 1 < NT){
      if constexpr (L == 8) asm volatile("s_waitcnt vmcnt(8)" ::: "memory");
      else                  asm volatile("s_waitcnt vmcnt(4)" ::: "memory");
    } else {
      asm volatile("s_waitcnt vmcnt(0)" ::: "memory");
    }
    __builtin_amdgcn_s_barrier();
    __builtin_amdgcn_sched_barrier(0);

    #pragma unroll
    for (int qr = 0; qr < FR / 4; ++qr){
      #pragma unroll
      for (int qc = 0; qc < FC / 2; ++qc){
        bf16x8 af[4][2], bfv[2][2];
        #pragma unroll
        for (int ii = 0; ii < 4; ++ii){
          int r = wr * WM + (qr * 4 + ii) * 16 + la;
          #pragma unroll
          for (int ks = 0; ks < 2; ++ks)
            af[ii][ks] = *(const bf16x8*)(curb + r * 64 + (((ks * 4 + lg) ^ (r & 7)) << 3));
        }
        #pragma unroll
        for (int jc = 0; jc < 2; ++jc){
          int rb = wc * WN + (qc * 2 + jc) * 16 + la;
          #pragma unroll
          for (int ks = 0; ks < 2; ++ks)
            bfv[jc][ks] = *(const bf16x8*)(curb + BM * 64 + rb * 64 + (((ks * 4 + lg) ^ (rb & 7)) << 3));
        }
        __builtin_amdgcn_s_setprio(1);
        #pragma unroll
        for (int ii = 0; ii < 4; ++ii)
          #pragma unroll
          for (int jc = 0; jc < 2; ++jc){
            acc[qr*4+ii][qc*2+jc] = __builtin_amdgcn_mfma_f32_16x16x32_bf16(
                af[ii][0], bfv[jc][0], acc[qr*4+ii][qc*2+jc], 0, 0, 0);
            acc[qr*4+ii][qc*2+jc] = __builtin_amdgcn_mfma_f32_16x16x32_bf16(
                af[ii][1], bfv[jc][1], acc[qr*4+ii][qc*2+jc], 0, 0, 0);
          }
        __builtin_amdgcn_s_setprio(0);
      }
    }
    __builtin_amdgcn_sched_barrier(0);
    __builtin_amdgcn_s_barrier();
    __builtin_amdgcn_sched_barrier(0);
    if (t + 2 < NT){
      #pragma unroll
      for (int l = 0; l < L; ++l)
        dp_issue<BM, BN>(A, Bt, curb, K, m0, n0, (t + 2) << 6, wave, lane, l);
    }
  }

  #pragma unroll
  for (int i = 0; i < FR; ++i){
    #pragma unroll
    for (int j = 0; j < FC; ++j){
      #pragma unroll
      for (int rr = 0; rr < 4; ++rr){
        int row = m0 + wr * WM + i * 16 + lg * 4 + rr;
        int col = n0 + wc * WN + j * 16 + la;
        float v = acc[i][j][rr];
        size_t idx = (size_t)row * N + col;
        if (EPI == EPI_F32){
          outF[idx] = v;
        } else if (EPI == EPI_RESID){
          outF[idx] = v + resid[idx];
        } else if (EPI == EPI_GATED){
          float gg = Gprev[idx];
          float s = gg / (1.f + __expf(-gg));
          outB[idx] = f2bf(s * v);
        } else { // EPI_QKV: q,k,v -> [B,H,T,64]; fold 1/32 into q
          int which = col >> 10;
          int hh = (col & 1023) >> 6;
          int d = col & 63;
          int bb = row >> 11, tt = row & 2047;
          size_t o = (((size_t)(bb * 16 + hh) * 2048) + tt) * 64 + d;
          if (which == 0)      qb[o] = f2bf(v * 0.03125f);
          else if (which == 1) kb[o] = f2bf(v);
          else                 vb[o] = f2bf(v);
        }
      }
    }
  }
}

// ---------------- flash attention (unchanged) ------------------------------
__global__ __launch_bounds__(512) void attn_kernel(
    const short* __restrict__ qb, const short* __restrict__ kb,
    const short* __restrict__ vtb, short* __restrict__ concat)
{
  const int T = 2048;
  int bh = blockIdx.y;
  int h = bh & 15, b = bh >> 4;
  int p = blockIdx.x;
  int tid = threadIdx.x, lane = tid & 63, wave = tid >> 6;
  int la = lane & 15, lg = lane >> 4;

  const short* Q  = qb  + (size_t)bh * T * 64;
  const short* Kg = kb  + (size_t)bh * T * 64;
  const short* Vt = vtb + (size_t)bh * 64 * T;

  __shared__ short Ks[2][64][72];
  __shared__ short Vs[2][64][72];
  __shared__ short Ps[8][16][72];

  int srow = tid >> 3, scol = (tid & 7) * 8;
  float slope = exp2f(-0.5f * (float)(h + 1));

  for (int half = 0; half < 2; ++half){
    int j = half ? (15 - p) : p;
    int ntiles = 2 * j + 2;

    int qr = j * 128 + wave * 16 + la;
    bf16x8 qf0 = *(const bf16x8*)(Q + (size_t)qr * 64 + lg * 8);
    bf16x8 qf1 = *(const bf16x8*)(Q + (size_t)qr * 64 + 32 + lg * 8);

    f32x4 o[4];
    float m_run[4], l_run[4];
    #pragma unroll
    for (int i = 0; i < 4; ++i){ o[i] = f32x4{0.f,0.f,0.f,0.f}; m_run[i] = -1e30f; l_run[i] = 0.f; }

    {
      bf16x8 k0 = *(const bf16x8*)(Kg + (size_t)srow * 64 + scol);
      bf16x8 v0 = *(const bf16x8*)(Vt + (size_t)srow * T + scol);
      *(bf16x8*)&Ks[0][srow][scol] = k0;
      *(bf16x8*)&Vs[0][srow][scol] = v0;
    }
    __syncthreads();

    int qpb = j * 128 + wave * 16 + lg * 4;

    for (int t = 0; t < ntiles; ++t){
      int cur = t & 1;
      int kv0 = t * 64;
      bool pref = (t + 1 < ntiles);
      bf16x8 kreg, vreg;
      if (pref){
        kreg = *(const bf16x8*)(Kg + (size_t)((t + 1) * 64 + srow) * 64 + scol);
        vreg = *(const bf16x8*)(Vt + (size_t)srow * T + (t + 1) * 64 + scol);
      }

      f32x4 s[4];
      #pragma unroll
      for (int nt = 0; nt < 4; ++nt){
        f32x4 a0 = f32x4{0.f,0.f,0.f,0.f};
        a0 = __builtin_amdgcn_mfma_f32_16x16x32_bf16(qf0, *(const bf16x8*)&Ks[cur][nt*16+la][lg*8],    a0, 0, 0, 0);
        a0 = __builtin_amdgcn_mfma_f32_16x16x32_bf16(qf1, *(const bf16x8*)&Ks[cur][nt*16+la][32+lg*8], a0, 0, 0, 0);
        s[nt] = a0;
      }

      float pbuf[4][4];
      #pragma unroll
      for (int r = 0; r < 4; ++r){
        int qpos = qpb + r;
        float mx = -1e30f;
        #pragma unroll
        for (int nt = 0; nt < 4; ++nt){
          int kvpos = kv0 + nt * 16 + la;
          float sc = s[nt][r] + slope * (float)(kvpos - qpos);
          sc = (kvpos <= qpos) ? sc : -1e30f;
          pbuf[nt][r] = sc;
          mx = fmaxf(mx, sc);
        }
        mx = fmaxf(mx, __shfl_xor(mx, 1, 16));
        mx = fmaxf(mx, __shfl_xor(mx, 2, 16));
        mx = fmaxf(mx, __shfl_xor(mx, 4, 16));
        mx = fmaxf(mx, __shfl_xor(mx, 8, 16));
        float mnew = fmaxf(m_run[r], mx);
        float alpha = __expf(m_run[r] - mnew);
        m_run[r] = mnew;
        float ps = 0.f;
        #pragma unroll
        for (int nt = 0; nt < 4; ++nt){
          float pe = __expf(pbuf[nt][r] - mnew);
          pbuf[nt][r] = pe;
          ps += pe;
        }
        ps += __shfl_xor(ps, 1, 16);
        ps += __shfl_xor(ps, 2, 16);
        ps += __shfl_xor(ps, 4, 16);
        ps += __shfl_xor(ps, 8, 16);
        l_run[r] = l_run[r] * alpha + ps;
        #pragma unroll
        for (int dt = 0; dt < 4; ++dt) o[dt][r] *= alpha;
      }

      #pragma unroll
      for (int r = 0; r < 4; ++r)
        #pragma unroll
        for (int nt = 0; nt < 4; ++nt)
          Ps[wave][lg * 4 + r][nt * 16 + la] = f2bf(pbuf[nt][r]);

      #pragma unroll
      for (int ks = 0; ks < 2; ++ks){
        bf16x8 pa = *(const bf16x8*)&Ps[wave][la][ks * 32 + lg * 8];
        #pragma unroll
        for (int dt = 0; dt < 4; ++dt){
          bf16x8 bv = *(const bf16x8*)&Vs[cur][dt * 16 + la][ks * 32 + lg * 8];
          o[dt] = __builtin_amdgcn_mfma_f32_16x16x32_bf16(pa, bv, o[dt], 0, 0, 0);
        }
      }

      if (pref){
        *(bf16x8*)&Ks[cur ^ 1][srow][scol] = kreg;
        *(bf16x8*)&Vs[cur ^ 1][srow][scol] = vreg;
      }
      __syncthreads();
    }

    #pragma unroll
    for (int dt = 0; dt < 4; ++dt){
      #pragma unroll
      for (int r = 0; r < 4; ++r){
        int qpos = qpb + r;
        int d = dt * 16 + la;
        float val = o[dt][r] / l_run[r];
        concat[((size_t)(b * 2048 + qpos)) * 1024 + h * 64 + d] = f2bf(val);
      }
    }
  }
}

extern "C" void kernel_launch(void* const* d_in, const int* in_sizes, int n_in,
                              void* d_out, int out_size, void* d_ws, size_t ws_size,
                              hipStream_t stream)
{
  (void)in_sizes; (void)n_in; (void)out_size; (void)ws_size;
  const float* x     = (const float*)d_in[0];
  const float* g1    = (const float*)d_in[1];
  const float* w_qkv = (const float*)d_in[2];
  const float* w_o   = (const float*)d_in[3];
  const float* g2    = (const float*)d_in[4];
  const float* W     = (const float*)d_in[5];
  const float* V     = (const float*)d_in[6];
  const float* W2    = (const float*)d_in[7];
  float* out = (float*)d_out;

  char* wsb = (char*)d_ws;
  size_t off = 0;
  auto alloc = [&](size_t bytes) -> void* {
    void* p = wsb + off;
    off += (bytes + 255) & ~(size_t)255;
    return p;
  };
  short* wqkvT = (short*)alloc((size_t)3072 * 1024 * 2);
  short* woT   = (short*)alloc((size_t)1024 * 1024 * 2);
  short* WT    = (short*)alloc((size_t)2816 * 1024 * 2);
  short* VT    = (short*)alloc((size_t)2816 * 1024 * 2);
  short* W2T   = (short*)alloc((size_t)1024 * 2816 * 2);
  short* h1    = (short*)alloc((size_t)4096 * 1024 * 2);
  short* qbuf  = (short*)alloc((size_t)4096 * 1024 * 2);
  short* kbuf  = (short*)alloc((size_t)4096 * 1024 * 2);
  short* vbuf  = (short*)alloc((size_t)4096 * 1024 * 2); // [B,H,T,64]
  short* vtbuf = (short*)alloc((size_t)4096 * 1024 * 2); // [B,H,64,T]
  short* conc  = (short*)alloc((size_t)4096 * 1024 * 2);
  float* x2    = (float*)alloc((size_t)4096 * 1024 * 4);
  short* h2    = (short*)alloc((size_t)4096 * 1024 * 2);
  float* G     = (float*)alloc((size_t)4096 * 2816 * 4);
  short* gated = (short*)alloc((size_t)4096 * 2816 * 2);

  dim3 tb(32, 8);
  hipLaunchKernelGGL(transpose_bf16_kernel, dim3(96, 32), tb, 0, stream, w_qkv, wqkvT, 1024, 3072, 3072, 1024);
  hipLaunchKernelGGL(transpose_bf16_kernel, dim3(32, 32), tb, 0, stream, w_o,   woT,   1024, 1024, 1024, 1024);
  hipLaunchKernelGGL(transpose_bf16_kernel, dim3(88, 32), tb, 0, stream, W,     WT,    1024, 2728, 2816, 1024);
  hipLaunchKernelGGL(transpose_bf16_kernel, dim3(88, 32), tb, 0, stream, V,     VT,    1024, 2728, 2816, 1024);
  hipLaunchKernelGGL(transpose_bf16_kernel, dim3(32, 88), tb, 0, stream, W2,    W2T,   2728, 1024, 1024, 2816);

  hipLaunchKernelGGL(rmsnorm_kernel, dim3(4096), dim3(256), 0, stream, x, g1, h1);

  // QKV: 4096 x 3072 x 1024, 256^2 tiles (192 blocks)
  hipLaunchKernelGGL((gemm_dp_kernel<256, 256, EPI_QKV>), dim3(192), dim3(512), 0, stream,
                     h1, wqkvT, 4096, 3072, 1024,
                     (float*)nullptr, (short*)nullptr, (const float*)nullptr, (const float*)nullptr,
                     qbuf, kbuf, vbuf);

  // V transpose for attention: [bh][t][d] -> [bh][d][t]
  hipLaunchKernelGGL(transpose_bb_kernel, dim3(64, 2, 32), tb, 0, stream, vbuf, vtbuf);

  hipLaunchKernelGGL(attn_kernel, dim3(8, 32), dim3(512), 0, stream, qbuf, kbuf, vtbuf, conc);

  // out-proj + residual: 4096 x 1024 x 1024, 128^2 tiles (256 blocks)
  hipLaunchKernelGGL((gemm_dp_kernel<128, 128, EPI_RESID>), dim3(256), dim3(512), 0, stream,
                     conc, woT, 4096, 1024, 1024,
                     x2, (short*)nullptr, x, (const float*)nullptr,
                     (short*)nullptr, (short*)nullptr, (short*)nullptr);

  hipLaunchKernelGGL(rmsnorm_kernel, dim3(4096), dim3(256), 0, stream, x2, g2, h2);

  // W: 4096 x 2816 x 1024 (176 blocks)
  hipLaunchKernelGGL((gemm_dp_kernel<256, 256, EPI_F32>), dim3(176), dim3(512), 0, stream,
                     h2, WT, 4096, 2816, 1024,
                     G, (short*)nullptr, (const float*)nullptr, (const float*)nullptr,
                     (short*)nullptr, (short*)nullptr, (short*)nullptr);

  // V-proj with SwiGLU gate epilogue (176 blocks)
  hipLaunchKernelGGL((gemm_dp_kernel<256, 256, EPI_GATED>), dim3(176), dim3(512), 0, stream,
                     h2, VT, 4096, 2816, 1024,
                     (float*)nullptr, gated, (const float*)nullptr, G,
                     (short*)nullptr, (short*)nullptr, (short*)nullptr);

  // W2 + residual: 4096 x 1024 x 2816, 128^2 tiles (256 blocks)
  hipLaunchKernelGGL((gemm_dp_kernel<128, 128, EPI_RESID>), dim3(256), dim3(512), 0, stream,
                     gated, W2T, 4096, 1024, 2816,
                     out, (short*)nullptr, x2, (const float*)nullptr,
                     (short*)nullptr, (short*)nullptr, (short*)nullptr);
}